// Round 5
// baseline (125.063 us; speedup 1.0000x reference)
//
#include <hip/hip_runtime.h>
#include <hip/hip_bf16.h>

// FactorizedTrilinear: out[b,z,x,c,dv] = sum_e p1[b,z,dv,e] p2[b,x,dv,e] p3[b,c,dv,e]
// B=4, Z=128, DV=4, IN=512, R=256. Output 4*128^3*4 fp32 = 134 MB (write-bound).
// R5: tri has ZERO barriers in the main loop. Per block-iter z is constant, so
// A-frag = p1[z] (uniform, L1-broadcast) * p2[x] (per-lane) built in-register;
// only p3 lives in LDS (64 KB, loaded once, XOR-swizzled granules). 2 blocks/CU,
// 16 free-running waves/CU, stores spread continuously (nontemporal).

typedef _Float16 f16;
typedef __attribute__((ext_vector_type(8))) _Float16 f16x8;
typedef __attribute__((ext_vector_type(4))) float f32x4;

// ---------------- Stage 0: W transpose + f16 convert ----------------
// Wt[mat][n][k] = (f16) W[mat][k][n];  W: [512][256] f32, Wt: [256][512] f16.
__global__ __launch_bounds__(256) void wt_kernel(
    const float* __restrict__ W1, const float* __restrict__ W2, const float* __restrict__ W3,
    f16* __restrict__ Wt) {
    const int mat = blockIdx.z;
    const float* __restrict__ W = (mat == 0) ? W1 : (mat == 1) ? W2 : W3;
    f16* __restrict__ T = Wt + (size_t)mat * 256 * 512;
    const int k0 = blockIdx.x * 64, n0 = blockIdx.y * 64;
    __shared__ float tile[64][65];
    const int t = threadIdx.x;
    const int c = t & 63, r4 = t >> 6;
#pragma unroll
    for (int i = 0; i < 16; ++i) {
        const int k = r4 * 16 + i;
        tile[k][c] = W[(size_t)(k0 + k) * 256 + n0 + c];
    }
    __syncthreads();
#pragma unroll
    for (int i = 0; i < 16; ++i) {
        const int n = r4 * 16 + i;
        T[(size_t)(n0 + n) * 512 + k0 + c] = (f16)tile[c][n];
    }
}

// ---------------- Stage 1: projections via f16 MFMA ----------------
// GEMM per matrix: M=2048 (rows m = b*512 + z*4 + dv), N=256, K=512.
// Wave tile 16m x 16n; block 4 waves = 16m x 64n; grid (128,4,3) = 1536 blocks
// (6 waves/SIMD). No LDS/barriers; K-loop unroll 2 for pipelining.
__global__ __launch_bounds__(256) void proj_kernel(
    const float* __restrict__ x1, const float* __restrict__ x2, const float* __restrict__ x3,
    const f16* __restrict__ Wt,
    const float* __restrict__ b1, const float* __restrict__ b2, const float* __restrict__ b3,
    f16* __restrict__ p1, f16* __restrict__ p2, f16* __restrict__ p3) {
    const int mat = blockIdx.z;
    const float* __restrict__ x    = (mat == 0) ? x1 : (mat == 1) ? x2 : x3;
    const f16*   __restrict__ T    = Wt + (size_t)mat * 131072;
    const float* __restrict__ bias = (mat == 0) ? b1 : (mat == 1) ? b2 : b3;
    f16* __restrict__ p = (mat == 0) ? p1 : (mat == 1) ? p2 : p3;

    const int tid  = threadIdx.x;
    const int lane = tid & 63;
    const int w    = tid >> 6;
    const int kq   = lane >> 4, ln = lane & 15;
    const int m_base = blockIdx.x * 16;
    const int n_base = blockIdx.y * 64 + w * 16;
    const int n      = n_base + ln;

    f32x4 acc = (f32x4){0.f, 0.f, 0.f, 0.f};

#pragma unroll 2
    for (int ks = 0; ks < 16; ++ks) {
        const int k0 = ks * 32 + kq * 8;
        const float* X = x + (size_t)(m_base + ln) * 512 + k0;
        f32x4 a0 = *(const f32x4*)X;
        f32x4 a1 = *(const f32x4*)(X + 4);
        f16x8 bv = *(const f16x8*)(T + (size_t)n * 512 + k0);
        f16x8 av;
        av[0] = (f16)a0[0]; av[1] = (f16)a0[1]; av[2] = (f16)a0[2]; av[3] = (f16)a0[3];
        av[4] = (f16)a1[0]; av[5] = (f16)a1[1]; av[6] = (f16)a1[2]; av[7] = (f16)a1[3];
        acc = __builtin_amdgcn_mfma_f32_16x16x32_f16(av, bv, acc, 0, 0, 0);
    }

    // C map (verified): row m = (lane>>4)*4 + reg, col n = lane&15.
    const float bn = bias[n];
#pragma unroll
    for (int r = 0; r < 4; ++r) {
        const int m  = m_base + kq * 4 + r;
        const int bb = m >> 9, z = (m >> 2) & 127, dv = m & 3;
        p[((bb * 4 + dv) * 128 + z) * 256 + n] = (f16)(acc[r] + bn);
    }
}

// ---------------- Stage 2: trilinear, barrier-free main loop ----------------
// Block = (b, ct c-tile of 32, rg z-group of 4). 512 thr = 8 waves, each wave
// owns 16 x-values per iter; 4 iters (z = rg*4+iter, all 128 x, 32 c, 4 dv).
// sB[dv][eg][cl] granules (16B = 8 f16 of p3), cl XOR (eg&7) swizzle ->
// conflict-free ds_read_b128. Loaded once; ONE barrier total.
// A-frag built in-register: p1[z] (wave-uniform) * p2[x] (per-lane), v_pk_mul_f16.
__global__ __launch_bounds__(512, 4) void tri_kernel(
    const f16* __restrict__ p1, const f16* __restrict__ p2,
    const f16* __restrict__ p3, float* __restrict__ out) {
    const int bi = blockIdx.x;
    const int rg = bi & 31;
    const int ct = (bi >> 5) & 3;
    const int b  = bi >> 7;

    const int tid  = threadIdx.x;
    const int lane = tid & 63;
    const int w    = tid >> 6;
    const int kq   = lane >> 4, ln = lane & 15;

    __shared__ __align__(16) f16 sB[4 * 32 * 32 * 8];   // 64 KB

    // ---- load p3 c-tile into LDS (once) ----
#pragma unroll
    for (int i = 0; i < 8; ++i) {
        const int g  = i * 512 + tid;
        const int eg = g & 31, cl = (g >> 5) & 31, dv = g >> 10;
        f16x8 v = *(const f16x8*)(p3 + (((b * 4 + dv) * 128 + ct * 32 + cl) << 8) + eg * 8);
        *(f16x8*)&sB[(((dv * 32 + eg) * 32) + (cl ^ (eg & 7))) * 8] = v;
    }
    __syncthreads();

#pragma unroll 1
    for (int iter = 0; iter < 4; ++iter) {
        const int z  = rg * 4 + iter;          // constant across the block-iter
        const int x0 = w * 16;                 // this wave's x-tile base

        f32x4 acc[2][4];
        const f32x4 zero = {0.f, 0.f, 0.f, 0.f};
#pragma unroll
        for (int c2 = 0; c2 < 2; ++c2)
#pragma unroll
            for (int dv = 0; dv < 4; ++dv) acc[c2][dv] = zero;

#pragma unroll 2
        for (int ks = 0; ks < 8; ++ks) {
            const int e0 = ks * 32 + kq * 8;
#pragma unroll
            for (int dv = 0; dv < 4; ++dv) {
                const int sl = b * 4 + dv;
                f16x8 u  = *(const f16x8*)(p1 + ((sl * 128 + z) << 8) + e0);        // uniform
                f16x8 pv = *(const f16x8*)(p2 + ((sl * 128 + x0 + ln) << 8) + e0);  // per-lane
                f16x8 af = u * pv;                                                  // pk_mul x4
                const int eg = ks * 4 + kq;
#pragma unroll
                for (int c2 = 0; c2 < 2; ++c2) {
                    const int cidx = c2 * 16 + ln;
                    f16x8 bf = *(const f16x8*)&sB[((dv * 32 + eg) * 32 + (cidx ^ (eg & 7))) * 8];
                    acc[c2][dv] = __builtin_amdgcn_mfma_f32_16x16x32_f16(
                        af, bf, acc[c2][dv], 0, 0, 0);
                }
            }
        }

        // ---- store: float4 over dv (innermost out dims), nontemporal ----
#pragma unroll
        for (int c2 = 0; c2 < 2; ++c2)
#pragma unroll
            for (int r = 0; r < 4; ++r) {
                const int x = x0 + kq * 4 + r;               // M-row = x
                const int c = ct * 32 + c2 * 16 + ln;
                const size_t idx = (size_t)((b * 128 + z) * 128 + x) * 128 + c;
                f32x4 v;
                v[0] = acc[c2][0][r];
                v[1] = acc[c2][1][r];
                v[2] = acc[c2][2][r];
                v[3] = acc[c2][3][r];
                __builtin_nontemporal_store(v, (f32x4*)(out + idx * 4));
            }
    }
}

extern "C" void kernel_launch(void* const* d_in, const int* in_sizes, int n_in,
                              void* d_out, int out_size, void* d_ws, size_t ws_size,
                              hipStream_t stream) {
    const float* x1 = (const float*)d_in[0];
    const float* x2 = (const float*)d_in[1];
    const float* x3 = (const float*)d_in[2];
    const float* W1 = (const float*)d_in[3];
    const float* b1 = (const float*)d_in[4];
    const float* W2 = (const float*)d_in[5];
    const float* b2 = (const float*)d_in[6];
    const float* W3 = (const float*)d_in[7];
    const float* b3 = (const float*)d_in[8];

    char* ws = (char*)d_ws;
    f16* p1 = (f16*)ws;                            // [16][128][256] f16 = 1 MB
    f16* p2 = (f16*)(ws + (1u << 20));             // 1 MB
    f16* p3 = (f16*)(ws + 2u * (1u << 20));        // 1 MB
    f16* Wt = (f16*)(ws + 3u * (1u << 20));        // 3 x 256 KB

    wt_kernel<<<dim3(8, 4, 3), 256, 0, stream>>>(W1, W2, W3, Wt);
    proj_kernel<<<dim3(128, 4, 3), 256, 0, stream>>>(x1, x2, x3, Wt, b1, b2, b3,
                                                     p1, p2, p3);
    tri_kernel<<<dim3(512), 512, 0, stream>>>(p1, p2, p3, (float*)d_out);
}

// Round 6
// 117.815 us; speedup vs baseline: 1.0615x; 1.0615x over previous
//
#include <hip/hip_runtime.h>
#include <hip/hip_bf16.h>

// FactorizedTrilinear: out[b,z,x,c,dv] = sum_e p1[b,z,dv,e] p2[b,x,dv,e] p3[b,c,dv,e]
// B=4, Z=128, DV=4, IN=512, R=256. Output 4*128^3*4 fp32 = 134 MB (write-bound).
// R6: tri uses 32x32x16 f16 MFMA, NO LDS, NO barriers. All operands per-lane
// from L2-resident p1/p2/p3 (3 MB, fits per-XCD L2). Wave = 32x x 32c x 2z x 4dv
// (acc 128 AGPR); 2-z reuse amortizes p2/p3 fragment loads. dv stays in-lane ->
// coalesced f32x4 stores over the innermost (d,v) output dims.

typedef _Float16 f16;
typedef __attribute__((ext_vector_type(8)))  _Float16 f16x8;
typedef __attribute__((ext_vector_type(4)))  float    f32x4;
typedef __attribute__((ext_vector_type(16))) float    f32x16;

// ---------------- Stage 0: W transpose + f16 convert ----------------
// Wt[mat][n][k] = (f16) W[mat][k][n];  W: [512][256] f32, Wt: [256][512] f16.
__global__ __launch_bounds__(256) void wt_kernel(
    const float* __restrict__ W1, const float* __restrict__ W2, const float* __restrict__ W3,
    f16* __restrict__ Wt) {
    const int mat = blockIdx.z;
    const float* __restrict__ W = (mat == 0) ? W1 : (mat == 1) ? W2 : W3;
    f16* __restrict__ T = Wt + (size_t)mat * 256 * 512;
    const int k0 = blockIdx.x * 64, n0 = blockIdx.y * 64;
    __shared__ float tile[64][65];
    const int t = threadIdx.x;
    const int c = t & 63, r4 = t >> 6;
#pragma unroll
    for (int i = 0; i < 16; ++i) {
        const int k = r4 * 16 + i;
        tile[k][c] = W[(size_t)(k0 + k) * 256 + n0 + c];
    }
    __syncthreads();
#pragma unroll
    for (int i = 0; i < 16; ++i) {
        const int n = r4 * 16 + i;
        T[(size_t)(n0 + n) * 512 + k0 + c] = (f16)tile[c][n];
    }
}

// ---------------- Stage 1: projections via 32x32x16 f16 MFMA ----------------
// GEMM per matrix: M=2048 (m = b*512 + z*4 + dv), N=256, K=512.
// Wave tile 32m x 32n; block 4 waves = 64m x 64n; grid (32,4,3). No LDS/barriers.
__global__ __launch_bounds__(256) void proj_kernel(
    const float* __restrict__ x1, const float* __restrict__ x2, const float* __restrict__ x3,
    const f16* __restrict__ Wt,
    const float* __restrict__ b1, const float* __restrict__ b2, const float* __restrict__ b3,
    f16* __restrict__ p1, f16* __restrict__ p2, f16* __restrict__ p3) {
    const int mat = blockIdx.z;
    const float* __restrict__ x    = (mat == 0) ? x1 : (mat == 1) ? x2 : x3;
    const f16*   __restrict__ T    = Wt + (size_t)mat * 131072;
    const float* __restrict__ bias = (mat == 0) ? b1 : (mat == 1) ? b2 : b3;
    f16* __restrict__ p = (mat == 0) ? p1 : (mat == 1) ? p2 : p3;

    const int tid  = threadIdx.x;
    const int lane = tid & 63;
    const int w    = tid >> 6;
    const int ln   = lane & 31;        // row within 32
    const int kq   = lane >> 5;        // k-half
    const int m0   = blockIdx.x * 64 + (w >> 1) * 32;
    const int n0   = blockIdx.y * 64 + (w & 1) * 32;

    f32x16 acc;
#pragma unroll
    for (int i = 0; i < 16; ++i) acc[i] = 0.f;

    const float* Xr = x + (size_t)(m0 + ln) * 512 + kq * 8;
    const f16*   Tr = T + (size_t)(n0 + ln) * 512 + kq * 8;

#pragma unroll 4
    for (int ks = 0; ks < 32; ++ks) {
        f32x4 a0 = *(const f32x4*)(Xr + ks * 16);
        f32x4 a1 = *(const f32x4*)(Xr + ks * 16 + 4);
        f16x8 bv = *(const f16x8*)(Tr + ks * 16);
        f16x8 av;
        av[0] = (f16)a0[0]; av[1] = (f16)a0[1]; av[2] = (f16)a0[2]; av[3] = (f16)a0[3];
        av[4] = (f16)a1[0]; av[5] = (f16)a1[1]; av[6] = (f16)a1[2]; av[7] = (f16)a1[3];
        acc = __builtin_amdgcn_mfma_f32_32x32x16_f16(av, bv, acc, 0, 0, 0);
    }

    // C/D map (m74/m101): col = lane&31, row = (reg&3) + 8*(reg>>2) + 4*(lane>>5).
    const int n = n0 + ln;
    const float bn = bias[n];
#pragma unroll
    for (int i = 0; i < 16; ++i) {
        const int m  = m0 + 4 * kq + (i & 3) + 8 * (i >> 2);
        const int bb = m >> 9, z = (m >> 2) & 127, dv = m & 3;
        p[((bb * 4 + dv) * 128 + z) * 256 + n] = (f16)(acc[i] + bn);
    }
}

// ---------------- Stage 2: trilinear, no LDS, no barriers ----------------
// Grid = b(4) x ct(4) x zp(64); block 256 thr = 4 waves = 4 x-tiles.
// Wave: 32x x 32c x 2z x 4dv, acc = 8 x f32x16 (128 AGPR).
// Per (dv,ks): u0,u1 (p1 rows z0,z1; half-wave-uniform 16B), pv (p2, per-lane),
// bq (p3, per-lane) -> a_zi = u_zi * pv (v_pk_mul_f16), 2 MFMA. All L2 hits.
__global__ __launch_bounds__(256, 2) void tri_kernel(
    const f16* __restrict__ p1, const f16* __restrict__ p2,
    const f16* __restrict__ p3, float* __restrict__ out) {
    const int bi = blockIdx.x;
    const int zp = bi & 63;            // z-pair index
    const int ct = (bi >> 6) & 3;
    const int b  = bi >> 8;

    const int tid  = threadIdx.x;
    const int lane = tid & 63;
    const int w    = tid >> 6;
    const int ln   = lane & 31;        // row/col within 32
    const int kq   = lane >> 5;        // k-half
    const int x0   = w * 32;
    const int c0   = ct * 32;
    const int z0   = zp * 2;

    f32x16 acc[2][4];
#pragma unroll
    for (int zi = 0; zi < 2; ++zi)
#pragma unroll
        for (int dv = 0; dv < 4; ++dv)
#pragma unroll
            for (int i = 0; i < 16; ++i) acc[zi][dv][i] = 0.f;

#pragma unroll
    for (int dv = 0; dv < 4; ++dv) {
        const int sl = b * 4 + dv;
        const f16* P1a = p1 + ((sl * 128 + z0) << 8) + kq * 8;          // z0 row
        const f16* P1b = P1a + 256;                                      // z1 row
        const f16* P2r = p2 + ((sl * 128 + x0 + ln) << 8) + kq * 8;      // per-lane x row
        const f16* P3r = p3 + ((sl * 128 + c0 + ln) << 8) + kq * 8;      // per-lane c row

#pragma unroll 4
        for (int ks = 0; ks < 16; ++ks) {
            f16x8 u0 = *(const f16x8*)(P1a + ks * 16);
            f16x8 u1 = *(const f16x8*)(P1b + ks * 16);
            f16x8 pv = *(const f16x8*)(P2r + ks * 16);
            f16x8 bq = *(const f16x8*)(P3r + ks * 16);
            f16x8 a0 = u0 * pv;    // 4 x v_pk_mul_f16
            f16x8 a1 = u1 * pv;
            acc[0][dv] = __builtin_amdgcn_mfma_f32_32x32x16_f16(a0, bq, acc[0][dv], 0, 0, 0);
            acc[1][dv] = __builtin_amdgcn_mfma_f32_32x32x16_f16(a1, bq, acc[1][dv], 0, 0, 0);
        }
    }

    // Epilogue: C/D map col = lane&31 -> c, row -> x; f32x4 gather over dv.
#pragma unroll
    for (int zi = 0; zi < 2; ++zi)
#pragma unroll
        for (int i = 0; i < 16; ++i) {
            const int x = x0 + 4 * kq + (i & 3) + 8 * (i >> 2);
            const int c = c0 + ln;
            const size_t idx = (size_t)((b * 128 + z0 + zi) * 128 + x) * 128 + c;
            f32x4 v;
            v[0] = acc[zi][0][i];
            v[1] = acc[zi][1][i];
            v[2] = acc[zi][2][i];
            v[3] = acc[zi][3][i];
            __builtin_nontemporal_store(v, (f32x4*)(out + idx * 4));
        }
}

extern "C" void kernel_launch(void* const* d_in, const int* in_sizes, int n_in,
                              void* d_out, int out_size, void* d_ws, size_t ws_size,
                              hipStream_t stream) {
    const float* x1 = (const float*)d_in[0];
    const float* x2 = (const float*)d_in[1];
    const float* x3 = (const float*)d_in[2];
    const float* W1 = (const float*)d_in[3];
    const float* b1 = (const float*)d_in[4];
    const float* W2 = (const float*)d_in[5];
    const float* b2 = (const float*)d_in[6];
    const float* W3 = (const float*)d_in[7];
    const float* b3 = (const float*)d_in[8];

    char* ws = (char*)d_ws;
    f16* p1 = (f16*)ws;                            // [16][128][256] f16 = 1 MB
    f16* p2 = (f16*)(ws + (1u << 20));             // 1 MB
    f16* p3 = (f16*)(ws + 2u * (1u << 20));        // 1 MB
    f16* Wt = (f16*)(ws + 3u * (1u << 20));        // 3 x 256 KB

    wt_kernel<<<dim3(8, 4, 3), 256, 0, stream>>>(W1, W2, W3, Wt);
    proj_kernel<<<dim3(32, 4, 3), 256, 0, stream>>>(x1, x2, x3, Wt, b1, b2, b3,
                                                    p1, p2, p3);
    tri_kernel<<<dim3(1024), 256, 0, stream>>>(p1, p2, p3, (float*)d_out);
}